// Round 13
// baseline (376.337 us; speedup 1.0000x reference)
//
#include <hip/hip_runtime.h>
#include <stdint.h>

#define N_EDGES 500000
#define N_NODES 100000
#define PREP_NG 2     // node-groups per wave in prep_p
#define TBINS 2560    // dist table bins, step 1/64, range [0,40) -- nearest-bin

typedef __attribute__((ext_vector_type(8))) short short8;
typedef __attribute__((ext_vector_type(4))) float floatx4;

// RNE (one-time prep only)
__device__ __forceinline__ uint16_t f2bf(float f) {
  union { float f; uint32_t u; } cv; cv.f = f;
  uint32_t u = cv.u;
  return (uint16_t)((u + 0x7FFFu + ((u >> 16) & 1u)) >> 16);
}
// truncating pack of two f32 -> bf16x2 (single v_perm_b32)
__device__ __forceinline__ uint32_t pk2bf(float lo, float hi) {
  return __builtin_amdgcn_perm(__float_as_uint(hi), __float_as_uint(lo), 0x07060302u);
}
__device__ __forceinline__ uint16_t bftrunc(float f) {
  return (uint16_t)(__float_as_uint(f) >> 16);
}
__device__ __forceinline__ float bf2f_lo(uint32_t u) { return __uint_as_float(u << 16); }
__device__ __forceinline__ float bf2f_hi(uint32_t u) { return __uint_as_float(u & 0xFFFF0000u); }
__device__ __forceinline__ float lrelu(float v) { return fmaxf(v, 0.001f * v); }

// async global->LDS, 16B/lane; lds dst is wave-uniform base (DMA adds lane*16)
__device__ __forceinline__ void gload_lds16(const uint16_t* g, uint16_t* l) {
  __builtin_amdgcn_global_load_lds(
      (const __attribute__((address_space(1))) void*)g,
      (__attribute__((address_space(3))) void*)l, 16, 0, 0);
}

// ============ prep0: W1/W2 + W0[0:256] -> MFMA-fragment order (bf16); BE0; pos copy ============
// fragment blob: frag[ks][nt][lane][j], element = W[k][n], k = ks*32+(lane>>4)*8+j,
// n = nt*16+(lane&15); a wave's B-frag (ks,nt) is one contiguous 1024B slab.
__global__ void prep0_kernel(const float* __restrict__ W0, const float* __restrict__ b0,
                             const float* __restrict__ W1, const float* __restrict__ W2,
                             const float* __restrict__ bemb,
                             uint16_t* __restrict__ w0ab, uint16_t* __restrict__ w1f,
                             uint16_t* __restrict__ w2f, float* __restrict__ be0f,
                             const float* __restrict__ pos, float* __restrict__ out, int npos) {
  int id = blockIdx.x * 256 + threadIdx.x;
  if (id < 32768) {                       // w0ab: ks(4) x ntt(16) x lane(64) x j(8)
    int f = id;
    int j = f & 7, lane = (f >> 3) & 63, ntt = (f >> 9) & 15, ks = f >> 13;
    int k = ks * 32 + (lane >> 4) * 8 + j;
    int row = (ntt < 8) ? k : (128 + k);            // ntt<8 -> P_a cols, else P_b cols
    int col = (ntt & 7) * 16 + (lane & 15);
    w0ab[f] = f2bf(W0[row * 128 + col]);
  } else if (id < 49152) {                // w1f
    int f = id - 32768;
    int j = f & 7, lane = (f >> 3) & 63, nt = (f >> 9) & 7, ks = f >> 12;
    int k = ks * 32 + (lane >> 4) * 8 + j;
    w1f[f] = f2bf(W1[k * 128 + nt * 16 + (lane & 15)]);
  } else if (id < 65536) {                // w2f
    int f = id - 49152;
    int j = f & 7, lane = (f >> 3) & 63, nt = (f >> 9) & 7, ks = f >> 12;
    int k = ks * 32 + (lane >> 4) * 8 + j;
    w2f[f] = f2bf(W2[k * 128 + nt * 16 + (lane & 15)]);
  } else if (id < 66048) {                // BE0[t][n] = bond_emb[t]@W0[256:320] + b0 (f32)
    int t = id - 65536; int ty = t >> 7, n = t & 127;
    float s = b0[n];
    for (int kk = 0; kk < 64; ++kk) s += bemb[ty * 64 + kk] * W0[(256 + kk) * 128 + n];
    be0f[t] = s;
  } else if (id - 66048 < npos) {         // pos -> out
    out[id - 66048] = pos[id - 66048];
  }
}

// ============ prep_t: T[t][b][n] = smear(dist_b)@W0[320:384] + BE0[t][n] (bf16) ============
// one block per bin: 64 exps once, then 512 dot-products of length 64
__global__ void prep_t_kernel(const float* __restrict__ W0, const float* __restrict__ be0f,
                              uint16_t* __restrict__ T) {
  __shared__ float rbf[64];
  int b = blockIdx.x;
  int t = threadIdx.x;
  float dist = (float)b * (1.0f / 64.0f);
  const float delta = 20.0f / 62.0f;
  const float coeff = -0.5f / (delta * delta);
  if (t < 64) {
    float v;
    if (t < 63) { float d = dist - (float)t * delta; v = __expf(coeff * d * d); }
    else v = (dist >= 20.0f) ? 1.0f : 0.0f;
    rbf[t] = v;
  }
  __syncthreads();
  float sum = 0.0f;
  for (int k = 0; k < 64; ++k) sum += rbf[k];
  float rs = 1.0f / sum;
  for (int o = t; o < 512; o += 256) {
    int ty = o >> 7, n = o & 127;
    float s = be0f[ty * 128 + n];
    for (int k = 0; k < 64; ++k) s += rbf[k] * rs * W0[(320 + k) * 128 + n];
    T[((size_t)(ty * TBINS + b)) * 128 + n] = f2bf(s);
  }
}

// ============ prep_p: P_a = nemb @ W0[0:128], P_b = nemb @ W0[128:256]  (f32 out) ============
// direct C-layout f32 stores (quad writes 64B segments) -- no transpose/pack pass
__global__ __attribute__((amdgpu_flat_work_group_size(256, 256), amdgpu_waves_per_eu(1, 4)))
void prep_p_kernel(const float* __restrict__ nemb, const uint16_t* __restrict__ w0ab,
                   float* __restrict__ Pa, float* __restrict__ Pb) {
  __shared__ __align__(16) uint16_t aLds[4 * PREP_NG * 16 * 136];
  const int tid = threadIdx.x;
  const int lane = tid & 63;
  const int wave = tid >> 6;
  const int n15 = lane & 15;
  const int quad = lane >> 4;
  uint16_t* myA = aLds + wave * (PREP_NG * 16 * 136);
  const int base = blockIdx.x * (64 * PREP_NG) + wave * (16 * PREP_NG);

  {
    const int le = lane >> 2, sub = lane & 3;
#pragma unroll
    for (int it = 0; it < PREP_NG; ++it) {
      int r = base + it * 16 + le; if (r >= N_NODES) r = N_NODES - 1;
      const float4* src = (const float4*)(nemb + (size_t)r * 128);
#pragma unroll
      for (int g = 0; g < 4; ++g) {
        float4 a = src[sub * 8 + g * 2], b = src[sub * 8 + g * 2 + 1];
        uint4 pk;
        pk.x = pk2bf(a.x, a.y); pk.y = pk2bf(a.z, a.w);
        pk.z = pk2bf(b.x, b.y); pk.w = pk2bf(b.z, b.w);
        *(uint4*)(myA + (it * 16 + le) * 136 + sub * 32 + g * 8) = pk;
      }
    }
  }

  const short8* wfv = (const short8*)w0ab + lane;
#pragma unroll
  for (int q = 0; q < 4; ++q) {
    short8 bfr[16];
#pragma unroll
    for (int ks = 0; ks < 4; ++ks)
#pragma unroll
      for (int nq = 0; nq < 4; ++nq)
        bfr[ks * 4 + nq] = wfv[(ks * 16 + q * 4 + nq) * 64];
#pragma unroll
    for (int it = 0; it < PREP_NG; ++it) {
      floatx4 acc[4];
#pragma unroll
      for (int nq = 0; nq < 4; ++nq) acc[nq] = (floatx4){0.f, 0.f, 0.f, 0.f};
#pragma unroll
      for (int ks = 0; ks < 4; ++ks) {
        short8 a = *(const short8*)(myA + (it * 16 + n15) * 136 + ks * 32 + quad * 8);
#pragma unroll
        for (int nq = 0; nq < 4; ++nq)
          acc[nq] = __builtin_amdgcn_mfma_f32_16x16x32_bf16(a, bfr[ks * 4 + nq], acc[nq], 0, 0, 0);
      }
      float* dst = (q < 2) ? Pa : Pb;
      int cbase = ((q & 1) * 4) * 16 + n15;
#pragma unroll
      for (int nq = 0; nq < 4; ++nq) {
        int c = cbase + nq * 16;
#pragma unroll
        for (int r = 0; r < 4; ++r) {
          int row = base + it * 16 + quad * 4 + r;
          if (row < N_NODES) dst[(size_t)row * 128 + c] = acc[nq][r];
        }
      }
    }
  }
}

// GEMM with B from LDS (staged weights): pure ds_read_b128 + MFMA
__device__ __forceinline__ void gemm_lds(const uint16_t* ws, const uint16_t* aRow,
                                         int lane, floatx4* acc) {
  short8 a[4];
#pragma unroll
  for (int ks = 0; ks < 4; ++ks) a[ks] = *(const short8*)(aRow + ks * 32);
#pragma unroll
  for (int ks = 0; ks < 4; ++ks)
#pragma unroll
    for (int nt = 0; nt < 8; ++nt) {
      short8 b = *(const short8*)(ws + (ks * 8 + nt) * 512 + lane * 8);
      acc[nt] = __builtin_amdgcn_mfma_f32_16x16x32_bf16(a[ks], b, acc[nt], 0, 0, 0);
    }
}

// ============ main: 64 edges/block, 4 waves, 16 edges/wave ============
// f32 Pa/Pb gathers (no unpack VALU), nearest-bin T. W1 staged into LDS at entry;
// W2 re-staged under epilogue-1's shadow. GEMM phases have ZERO global loads.
__global__ __attribute__((amdgpu_flat_work_group_size(256, 256)))
void bond_mlp_kernel(const float* __restrict__ x,
                     const int* __restrict__ bidx, const int* __restrict__ btyp,
                     const float* __restrict__ Pa, const float* __restrict__ Pb,
                     const uint16_t* __restrict__ Tt, const uint16_t* __restrict__ w1f,
                     const uint16_t* __restrict__ w2f,
                     const float* __restrict__ b1, const float* __restrict__ ln1w,
                     const float* __restrict__ ln1b,
                     const float* __restrict__ b2, const float* __restrict__ ln2w,
                     const float* __restrict__ ln2b,
                     const float* __restrict__ Wo, const float* __restrict__ bo,
                     float* __restrict__ out) {
  __shared__ __align__(16) uint16_t wstage[16384];          // 32768 B staged weights
  __shared__ __align__(16) uint16_t hA_all[4 * 16 * 136];   // 17408 B
  __shared__ float u_lds[64][3];
  __shared__ int ij_lds[64][2];

  const int tid = threadIdx.x;
  const int lane = tid & 63;
  const int wave = tid >> 6;
  const int n15 = lane & 15;
  const int quad = lane >> 4;

  uint16_t* hA = hA_all + wave * (16 * 136);

  // stage W1 (32KB, 8 DMA instrs/wave) -- drains at barrier 1, overlapped w/ phase 1
#pragma unroll
  for (int j = 0; j < 8; ++j)
    gload_lds16(w1f + (wave * 8 + j) * 512 + lane * 8, wstage + (wave * 8 + j) * 512);

  // ---- phase 1: h0 = lrelu(Pa[i] + Pb[j] + T[bin]) -> hA (A-layout, bf16) ----
  {
    const int le = lane >> 2, sub = lane & 3;   // 4 lanes per edge
    const int gr = wave * 16 + le;
    const int ge = blockIdx.x * 64 + gr;
    const bool valid = ge < N_EDGES;
    int vi = 0, vj = 0, bt = 0;
    if (valid) { vi = bidx[2 * ge]; vj = bidx[2 * ge + 1]; bt = btyp[ge]; }
    float dx, dy, dz;
    if (valid) {
      dx = x[3 * vi]     - x[3 * vj];
      dy = x[3 * vi + 1] - x[3 * vj + 1];
      dz = x[3 * vi + 2] - x[3 * vj + 2];
    } else { dx = 1.0f; dy = 0.0f; dz = 0.0f; }
    float dist = sqrtf(dx * dx + dy * dy + dz * dz);
    float rinv = 1.0f / dist;
    if (sub == 0) {
      u_lds[gr][0] = dx * rinv; u_lds[gr][1] = dy * rinv; u_lds[gr][2] = dz * rinv;
      ij_lds[gr][0] = vi; ij_lds[gr][1] = vj;
    }
    int bi = (int)(dist * 64.0f + 0.5f);
    if (bi > TBINS - 1) bi = TBINS - 1;
    const float4* pa = (const float4*)(Pa + (size_t)vi * 128 + sub * 32);
    const float4* pb = (const float4*)(Pb + (size_t)vj * 128 + sub * 32);
    const uint4* tp = (const uint4*)(Tt + ((size_t)(bt * TBINS + bi)) * 128 + sub * 32);
#pragma unroll
    for (int g = 0; g < 4; ++g) {
      float4 a0 = pa[2 * g], a1 = pa[2 * g + 1];
      float4 q0 = pb[2 * g], q1 = pb[2 * g + 1];
      uint4 tv = tp[g];
      uint4 pk;
      pk.x = pk2bf(lrelu(a0.x + q0.x + bf2f_lo(tv.x)), lrelu(a0.y + q0.y + bf2f_hi(tv.x)));
      pk.y = pk2bf(lrelu(a0.z + q0.z + bf2f_lo(tv.y)), lrelu(a0.w + q0.w + bf2f_hi(tv.y)));
      pk.z = pk2bf(lrelu(a1.x + q1.x + bf2f_lo(tv.z)), lrelu(a1.y + q1.y + bf2f_hi(tv.z)));
      pk.w = pk2bf(lrelu(a1.z + q1.z + bf2f_lo(tv.w)), lrelu(a1.w + q1.w + bf2f_hi(tv.w)));
      *(uint4*)(hA + le * 136 + sub * 32 + g * 8) = pk;
    }
  }
  __syncthreads();                       // #1: W1 staged + hA ready

  const uint16_t* aRow = hA + n15 * 136 + quad * 8;

  floatx4 acc[8];
#pragma unroll
  for (int nt = 0; nt < 8; ++nt) acc[nt] = (floatx4){0.f, 0.f, 0.f, 0.f};
  gemm_lds(wstage, aRow, lane, acc);     // L1, B from LDS

  __syncthreads();                       // #2: all waves done reading W1
  // stage W2 into same buffer -- drains at barrier 3, hidden under epilogue 1
#pragma unroll
  for (int j = 0; j < 8; ++j)
    gload_lds16(w2f + (wave * 8 + j) * 512 + lane * 8, wstage + (wave * 8 + j) * 512);

  // epilogue 1: +b1, LN, lrelu -> hA
  {
    float bv[8], wv[8], bb2[8];
#pragma unroll
    for (int nt = 0; nt < 8; ++nt) {
      int col = nt * 16 + n15;
      bv[nt] = b1[col]; wv[nt] = ln1w[col]; bb2[nt] = ln1b[col];
    }
    float s[4] = {0,0,0,0}, q[4] = {0,0,0,0};
#pragma unroll
    for (int nt = 0; nt < 8; ++nt)
#pragma unroll
      for (int r = 0; r < 4; ++r) { float v = acc[nt][r] + bv[nt]; s[r] += v; q[r] += v * v; }
#pragma unroll
    for (int m = 1; m <= 8; m <<= 1)
#pragma unroll
      for (int r = 0; r < 4; ++r) { s[r] += __shfl_xor(s[r], m); q[r] += __shfl_xor(q[r], m); }
    float mean[4], rstd[4];
#pragma unroll
    for (int r = 0; r < 4; ++r) {
      mean[r] = s[r] * (1.0f / 128.0f);
      float var = q[r] * (1.0f / 128.0f) - mean[r] * mean[r];
      rstd[r] = rsqrtf(var + 1e-5f);
    }
#pragma unroll
    for (int nt = 0; nt < 8; ++nt)
#pragma unroll
      for (int r = 0; r < 4; ++r) {
        float v = acc[nt][r] + bv[nt];
        float vn = (v - mean[r]) * rstd[r] * wv[nt] + bb2[nt];
        hA[(quad * 4 + r) * 136 + nt * 16 + n15] = bftrunc(lrelu(vn));
      }
  }
  __syncthreads();                       // #3: W2 staged (hA is wave-private)

#pragma unroll
  for (int nt = 0; nt < 8; ++nt) acc[nt] = (floatx4){0.f, 0.f, 0.f, 0.f};
  gemm_lds(wstage, aRow, lane, acc);     // L2, B from LDS

  // epilogue 2: +b2, LN, lrelu, force = h@Wo + bo, scatter atomics
  {
    float bv[8], wv[8], bb2[8], wo0[8], wo1[8];
#pragma unroll
    for (int nt = 0; nt < 8; ++nt) {
      int col = nt * 16 + n15;
      bv[nt] = b2[col]; wv[nt] = ln2w[col]; bb2[nt] = ln2b[col];
      wo0[nt] = Wo[2 * col]; wo1[nt] = Wo[2 * col + 1];
    }
    float s[4] = {0,0,0,0}, q[4] = {0,0,0,0};
#pragma unroll
    for (int nt = 0; nt < 8; ++nt)
#pragma unroll
      for (int r = 0; r < 4; ++r) { float v = acc[nt][r] + bv[nt]; s[r] += v; q[r] += v * v; }
#pragma unroll
    for (int m = 1; m <= 8; m <<= 1)
#pragma unroll
      for (int r = 0; r < 4; ++r) { s[r] += __shfl_xor(s[r], m); q[r] += __shfl_xor(q[r], m); }
    float mean[4], rstd[4];
#pragma unroll
    for (int r = 0; r < 4; ++r) {
      mean[r] = s[r] * (1.0f / 128.0f);
      float var = q[r] * (1.0f / 128.0f) - mean[r] * mean[r];
      rstd[r] = rsqrtf(var + 1e-5f);
    }
    float f0[4] = {0,0,0,0}, f1[4] = {0,0,0,0};
#pragma unroll
    for (int nt = 0; nt < 8; ++nt)
#pragma unroll
      for (int r = 0; r < 4; ++r) {
        float v = acc[nt][r] + bv[nt];
        float vn = lrelu((v - mean[r]) * rstd[r] * wv[nt] + bb2[nt]);
        f0[r] += vn * wo0[nt];
        f1[r] += vn * wo1[nt];
      }
#pragma unroll
    for (int m = 1; m <= 8; m <<= 1)
#pragma unroll
      for (int r = 0; r < 4; ++r) { f0[r] += __shfl_xor(f0[r], m); f1[r] += __shfl_xor(f1[r], m); }

    if (n15 < 4) {
      int gr = wave * 16 + quad * 4 + n15;
      int ge2 = blockIdx.x * 64 + gr;
      if (ge2 < N_EDGES) {
        float F0 = (n15 == 0) ? f0[0] : (n15 == 1) ? f0[1] : (n15 == 2) ? f0[2] : f0[3];
        float F1 = (n15 == 0) ? f1[0] : (n15 == 1) ? f1[1] : (n15 == 2) ? f1[2] : f1[3];
        F0 += bo[0]; F1 += bo[1];
        float ux = u_lds[gr][0], uy = u_lds[gr][1], uz = u_lds[gr][2];
        int ii = ij_lds[gr][0], jj = ij_lds[gr][1];
        float c0 = 0.5f * F0;          // STEP * force0, along +u
        float c1 = -0.5f * F1;         // STEP * force1, along -u
        atomicAdd(out + 3 * ii,     c0 * ux);
        atomicAdd(out + 3 * ii + 1, c0 * uy);
        atomicAdd(out + 3 * ii + 2, c0 * uz);
        atomicAdd(out + 3 * jj,     c1 * ux);
        atomicAdd(out + 3 * jj + 1, c1 * uy);
        atomicAdd(out + 3 * jj + 2, c1 * uz);
      }
    }
  }
}

extern "C" void kernel_launch(void* const* d_in, const int* in_sizes, int n_in,
                              void* d_out, int out_size, void* d_ws, size_t ws_size,
                              hipStream_t stream) {
  const float* x    = (const float*)d_in[0];
  const float* pos  = (const float*)d_in[1];
  const float* nemb = (const float*)d_in[2];
  const int*   bidx = (const int*)d_in[3];
  const int*   btyp = (const int*)d_in[4];
  const float* bemb = (const float*)d_in[5];
  const float* W0   = (const float*)d_in[6];
  const float* b0   = (const float*)d_in[7];
  const float* W1   = (const float*)d_in[8];
  const float* b1   = (const float*)d_in[9];
  const float* ln1w = (const float*)d_in[10];
  const float* ln1b = (const float*)d_in[11];
  const float* W2   = (const float*)d_in[12];
  const float* b2   = (const float*)d_in[13];
  const float* ln2w = (const float*)d_in[14];
  const float* ln2b = (const float*)d_in[15];
  const float* Wo   = (const float*)d_in[16];
  const float* bo   = (const float*)d_in[17];
  float* out = (float*)d_out;

  // ws: frag weights 128KB + be0 2KB + T 2.62MB + Pa/Pb f32 102.4MB (~105MB)
  uint16_t* w0ab = (uint16_t*)d_ws;                 // 32768 bf16
  uint16_t* w1f  = w0ab + 32768;                    // 16384
  uint16_t* w2f  = w1f + 16384;                     // 16384
  float*    be0f = (float*)(w2f + 16384);           // 512 f32
  uint16_t* Tt   = (uint16_t*)(be0f + 512);         // 4*TBINS*128 bf16
  float*    Pa   = (float*)(Tt + (size_t)4 * TBINS * 128);  // N_NODES*128 f32
  float*    Pb   = Pa + (size_t)N_NODES * 128;              // N_NODES*128 f32

  prep0_kernel<<<(66048 + out_size + 255) / 256, 256, 0, stream>>>(
      W0, b0, W1, W2, bemb, w0ab, w1f, w2f, be0f, pos, out, out_size);
  prep_t_kernel<<<TBINS, 256, 0, stream>>>(W0, be0f, Tt);
  prep_p_kernel<<<(N_NODES + 64 * PREP_NG - 1) / (64 * PREP_NG), 256, 0, stream>>>(
      nemb, w0ab, Pa, Pb);
  bond_mlp_kernel<<<(N_EDGES + 63) / 64, 256, 0, stream>>>(
      x, bidx, btyp, Pa, Pb, Tt, w1f, w2f,
      b1, ln1w, ln1b, b2, ln2w, ln2b, Wo, bo, out);
}

// Round 14
// 350.854 us; speedup vs baseline: 1.0726x; 1.0726x over previous
//
#include <hip/hip_runtime.h>
#include <stdint.h>

#define N_EDGES 500000
#define N_NODES 100000
#define PREP_NG 2     // node-groups per wave in prep_p
#define TBINS 1280    // dist table bins, step 1/32, range [0,40)

typedef __attribute__((ext_vector_type(8))) short short8;
typedef __attribute__((ext_vector_type(4))) float floatx4;

// RNE (one-time prep only)
__device__ __forceinline__ uint16_t f2bf(float f) {
  union { float f; uint32_t u; } cv; cv.f = f;
  uint32_t u = cv.u;
  return (uint16_t)((u + 0x7FFFu + ((u >> 16) & 1u)) >> 16);
}
// truncating pack of two f32 -> bf16x2 (single v_perm_b32)
__device__ __forceinline__ uint32_t pk2bf(float lo, float hi) {
  return __builtin_amdgcn_perm(__float_as_uint(hi), __float_as_uint(lo), 0x07060302u);
}
__device__ __forceinline__ uint16_t bftrunc(float f) {
  return (uint16_t)(__float_as_uint(f) >> 16);
}
__device__ __forceinline__ float bf2f_lo(uint32_t u) { return __uint_as_float(u << 16); }
__device__ __forceinline__ float bf2f_hi(uint32_t u) { return __uint_as_float(u & 0xFFFF0000u); }
__device__ __forceinline__ float lrelu(float v) { return fmaxf(v, 0.001f * v); }

// async global->LDS, 16B/lane; lds dst is wave-uniform base (DMA adds lane*16)
__device__ __forceinline__ void gload_lds16(const uint16_t* g, uint16_t* l) {
  __builtin_amdgcn_global_load_lds(
      (const __attribute__((address_space(1))) void*)g,
      (__attribute__((address_space(3))) void*)l, 16, 0, 0);
}

// ============ prep0: W1/W2 + W0[0:256] -> MFMA-fragment order (bf16); BE0; pos copy ============
// fragment blob: frag[ks][nt][lane][j], element = W[k][n], k = ks*32+(lane>>4)*8+j,
// n = nt*16+(lane&15); a wave's B-frag (ks,nt) is one contiguous 1024B slab.
__global__ void prep0_kernel(const float* __restrict__ W0, const float* __restrict__ b0,
                             const float* __restrict__ W1, const float* __restrict__ W2,
                             const float* __restrict__ bemb,
                             uint16_t* __restrict__ w0ab, uint16_t* __restrict__ w1f,
                             uint16_t* __restrict__ w2f, float* __restrict__ be0f,
                             const float* __restrict__ pos, float* __restrict__ out, int npos) {
  int id = blockIdx.x * 256 + threadIdx.x;
  if (id < 32768) {                       // w0ab: ks(4) x ntt(16) x lane(64) x j(8)
    int f = id;
    int j = f & 7, lane = (f >> 3) & 63, ntt = (f >> 9) & 15, ks = f >> 13;
    int k = ks * 32 + (lane >> 4) * 8 + j;
    int row = (ntt < 8) ? k : (128 + k);            // ntt<8 -> P_a cols, else P_b cols
    int col = (ntt & 7) * 16 + (lane & 15);
    w0ab[f] = f2bf(W0[row * 128 + col]);
  } else if (id < 49152) {                // w1f
    int f = id - 32768;
    int j = f & 7, lane = (f >> 3) & 63, nt = (f >> 9) & 7, ks = f >> 12;
    int k = ks * 32 + (lane >> 4) * 8 + j;
    w1f[f] = f2bf(W1[k * 128 + nt * 16 + (lane & 15)]);
  } else if (id < 65536) {                // w2f
    int f = id - 49152;
    int j = f & 7, lane = (f >> 3) & 63, nt = (f >> 9) & 7, ks = f >> 12;
    int k = ks * 32 + (lane >> 4) * 8 + j;
    w2f[f] = f2bf(W2[k * 128 + nt * 16 + (lane & 15)]);
  } else if (id < 66048) {                // BE0[t][n] = bond_emb[t]@W0[256:320] + b0 (f32)
    int t = id - 65536; int ty = t >> 7, n = t & 127;
    float s = b0[n];
    for (int kk = 0; kk < 64; ++kk) s += bemb[ty * 64 + kk] * W0[(256 + kk) * 128 + n];
    be0f[t] = s;
  } else if (id - 66048 < npos) {         // pos -> out
    out[id - 66048] = pos[id - 66048];
  }
}

// ============ prep_t: T[t][b][n] = smear(dist_b)@W0[320:384] + BE0[t][n] (bf16) ============
// one block per bin: 64 exps once, then 512 dot-products of length 64
__global__ void prep_t_kernel(const float* __restrict__ W0, const float* __restrict__ be0f,
                              uint16_t* __restrict__ T) {
  __shared__ float rbf[64];
  int b = blockIdx.x;
  int t = threadIdx.x;
  float dist = (float)b * (1.0f / 32.0f);
  const float delta = 20.0f / 62.0f;
  const float coeff = -0.5f / (delta * delta);
  if (t < 64) {
    float v;
    if (t < 63) { float d = dist - (float)t * delta; v = __expf(coeff * d * d); }
    else v = (dist >= 20.0f) ? 1.0f : 0.0f;
    rbf[t] = v;
  }
  __syncthreads();
  float sum = 0.0f;
  for (int k = 0; k < 64; ++k) sum += rbf[k];
  float rs = 1.0f / sum;
  for (int o = t; o < 512; o += 256) {
    int ty = o >> 7, n = o & 127;
    float s = be0f[ty * 128 + n];
    for (int k = 0; k < 64; ++k) s += rbf[k] * rs * W0[(320 + k) * 128 + n];
    T[((size_t)(ty * TBINS + b)) * 128 + n] = f2bf(s);
  }
}

// ============ prep_p: P_a = nemb @ W0[0:128], P_b = nemb @ W0[128:256] (bf16) ============
__global__ __attribute__((amdgpu_flat_work_group_size(256, 256), amdgpu_waves_per_eu(1, 4)))
void prep_p_kernel(const float* __restrict__ nemb, const uint16_t* __restrict__ w0ab,
                   uint16_t* __restrict__ Pa, uint16_t* __restrict__ Pb) {
  __shared__ __align__(16) uint16_t aLds[4 * PREP_NG * 16 * 136];
  const int tid = threadIdx.x;
  const int lane = tid & 63;
  const int wave = tid >> 6;
  const int n15 = lane & 15;
  const int quad = lane >> 4;
  uint16_t* myA = aLds + wave * (PREP_NG * 16 * 136);
  const int base = blockIdx.x * (64 * PREP_NG) + wave * (16 * PREP_NG);

  {
    const int le = lane >> 2, sub = lane & 3;
#pragma unroll
    for (int it = 0; it < PREP_NG; ++it) {
      int r = base + it * 16 + le; if (r >= N_NODES) r = N_NODES - 1;
      const float4* src = (const float4*)(nemb + (size_t)r * 128);
#pragma unroll
      for (int g = 0; g < 4; ++g) {
        float4 a = src[sub * 8 + g * 2], b = src[sub * 8 + g * 2 + 1];
        uint4 pk;
        pk.x = pk2bf(a.x, a.y); pk.y = pk2bf(a.z, a.w);
        pk.z = pk2bf(b.x, b.y); pk.w = pk2bf(b.z, b.w);
        *(uint4*)(myA + (it * 16 + le) * 136 + sub * 32 + g * 8) = pk;
      }
    }
  }

  const short8* wfv = (const short8*)w0ab + lane;
#pragma unroll
  for (int q = 0; q < 4; ++q) {
    short8 bfr[16];
#pragma unroll
    for (int ks = 0; ks < 4; ++ks)
#pragma unroll
      for (int nq = 0; nq < 4; ++nq)
        bfr[ks * 4 + nq] = wfv[(ks * 16 + q * 4 + nq) * 64];
#pragma unroll
    for (int it = 0; it < PREP_NG; ++it) {
      floatx4 acc[4];
#pragma unroll
      for (int nq = 0; nq < 4; ++nq) acc[nq] = (floatx4){0.f, 0.f, 0.f, 0.f};
#pragma unroll
      for (int ks = 0; ks < 4; ++ks) {
        short8 a = *(const short8*)(myA + (it * 16 + n15) * 136 + ks * 32 + quad * 8);
#pragma unroll
        for (int nq = 0; nq < 4; ++nq)
          acc[nq] = __builtin_amdgcn_mfma_f32_16x16x32_bf16(a, bfr[ks * 4 + nq], acc[nq], 0, 0, 0);
      }
      uint16_t* dst = (q < 2) ? Pa : Pb;
      int cbase = ((q & 1) * 4) * 16 + n15;
#pragma unroll
      for (int nq = 0; nq < 4; ++nq) {
        int c = cbase + nq * 16;
#pragma unroll
        for (int r = 0; r < 4; ++r) {
          int row = base + it * 16 + quad * 4 + r;
          if (row < N_NODES) dst[(size_t)row * 128 + c] = bftrunc(acc[nq][r]);
        }
      }
    }
  }
}

// GEMM with B from LDS (staged weights): pure ds_read_b128 + MFMA
__device__ __forceinline__ void gemm_lds(const uint16_t* ws, const uint16_t* aRow,
                                         int lane, floatx4* acc) {
  short8 a[4];
#pragma unroll
  for (int ks = 0; ks < 4; ++ks) a[ks] = *(const short8*)(aRow + ks * 32);
#pragma unroll
  for (int ks = 0; ks < 4; ++ks)
#pragma unroll
    for (int nt = 0; nt < 8; ++nt) {
      short8 b = *(const short8*)(ws + (ks * 8 + nt) * 512 + lane * 8);
      acc[nt] = __builtin_amdgcn_mfma_f32_16x16x32_bf16(a[ks], b, acc[nt], 0, 0, 0);
    }
}

// ============ main: 64 edges/block, 4 waves, 16 edges/wave ============
// W1 staged into LDS at entry (drains at barrier 1, hidden under phase-1 gathers);
// W2 re-staged into the same buffer under epilogue-1's shadow. GEMM phases have
// ZERO global loads. 51456B LDS -> 3 blocks/CU. [Empirical best: R9 config]
__global__ __attribute__((amdgpu_flat_work_group_size(256, 256)))
void bond_mlp_kernel(const float* __restrict__ x,
                     const int* __restrict__ bidx, const int* __restrict__ btyp,
                     const uint16_t* __restrict__ Pa, const uint16_t* __restrict__ Pb,
                     const uint16_t* __restrict__ Tt, const uint16_t* __restrict__ w1f,
                     const uint16_t* __restrict__ w2f,
                     const float* __restrict__ b1, const float* __restrict__ ln1w,
                     const float* __restrict__ ln1b,
                     const float* __restrict__ b2, const float* __restrict__ ln2w,
                     const float* __restrict__ ln2b,
                     const float* __restrict__ Wo, const float* __restrict__ bo,
                     float* __restrict__ out) {
  __shared__ __align__(16) uint16_t wstage[16384];          // 32768 B staged weights
  __shared__ __align__(16) uint16_t hA_all[4 * 16 * 136];   // 17408 B
  __shared__ float u_lds[64][3];
  __shared__ int ij_lds[64][2];

  const int tid = threadIdx.x;
  const int lane = tid & 63;
  const int wave = tid >> 6;
  const int n15 = lane & 15;
  const int quad = lane >> 4;

  uint16_t* hA = hA_all + wave * (16 * 136);

  // stage W1 (32KB, 8 DMA instrs/wave) -- drains at barrier 1, overlapped w/ phase 1
#pragma unroll
  for (int j = 0; j < 8; ++j)
    gload_lds16(w1f + (wave * 8 + j) * 512 + lane * 8, wstage + (wave * 8 + j) * 512);

  // ---- phase 1: h0 = lrelu(Pa[i]+Pb[j]+lerp(T[t],dist)) -> hA (A-layout, bf16) ----
  {
    const int le = lane >> 2, sub = lane & 3;   // 4 lanes per edge
    const int gr = wave * 16 + le;
    const int ge = blockIdx.x * 64 + gr;
    const bool valid = ge < N_EDGES;
    int vi = 0, vj = 0, bt = 0;
    if (valid) { vi = bidx[2 * ge]; vj = bidx[2 * ge + 1]; bt = btyp[ge]; }
    float dx, dy, dz;
    if (valid) {
      dx = x[3 * vi]     - x[3 * vj];
      dy = x[3 * vi + 1] - x[3 * vj + 1];
      dz = x[3 * vi + 2] - x[3 * vj + 2];
    } else { dx = 1.0f; dy = 0.0f; dz = 0.0f; }
    float dist = sqrtf(dx * dx + dy * dy + dz * dz);
    float rinv = 1.0f / dist;
    if (sub == 0) {
      u_lds[gr][0] = dx * rinv; u_lds[gr][1] = dy * rinv; u_lds[gr][2] = dz * rinv;
      ij_lds[gr][0] = vi; ij_lds[gr][1] = vj;
    }
    float fb = fminf(dist, 39.5f) * 32.0f;
    int bi = (int)fb;
    float w = fb - (float)bi;
    const uint4* pa = (const uint4*)(Pa + (size_t)vi * 128 + sub * 32);
    const uint4* pb = (const uint4*)(Pb + (size_t)vj * 128 + sub * 32);
    const uint16_t* trow = Tt + ((size_t)(bt * TBINS + bi)) * 128 + sub * 32;
    const uint4* t0p = (const uint4*)trow;
    const uint4* t1p = (const uint4*)(trow + 128);
#pragma unroll
    for (int g = 0; g < 4; ++g) {
      uint4 av = pa[g], bv = pb[g], t0 = t0p[g], t1 = t1p[g];
      uint4 pk;
      {
        float lo = bf2f_lo(av.x) + bf2f_lo(bv.x), hi = bf2f_hi(av.x) + bf2f_hi(bv.x);
        float l0 = bf2f_lo(t0.x), l1 = bf2f_lo(t1.x), h0 = bf2f_hi(t0.x), h1 = bf2f_hi(t1.x);
        pk.x = pk2bf(lrelu(lo + l0 + w * (l1 - l0)), lrelu(hi + h0 + w * (h1 - h0)));
      }
      {
        float lo = bf2f_lo(av.y) + bf2f_lo(bv.y), hi = bf2f_hi(av.y) + bf2f_hi(bv.y);
        float l0 = bf2f_lo(t0.y), l1 = bf2f_lo(t1.y), h0 = bf2f_hi(t0.y), h1 = bf2f_hi(t1.y);
        pk.y = pk2bf(lrelu(lo + l0 + w * (l1 - l0)), lrelu(hi + h0 + w * (h1 - h0)));
      }
      {
        float lo = bf2f_lo(av.z) + bf2f_lo(bv.z), hi = bf2f_hi(av.z) + bf2f_hi(bv.z);
        float l0 = bf2f_lo(t0.z), l1 = bf2f_lo(t1.z), h0 = bf2f_hi(t0.z), h1 = bf2f_hi(t1.z);
        pk.z = pk2bf(lrelu(lo + l0 + w * (l1 - l0)), lrelu(hi + h0 + w * (h1 - h0)));
      }
      {
        float lo = bf2f_lo(av.w) + bf2f_lo(bv.w), hi = bf2f_hi(av.w) + bf2f_hi(bv.w);
        float l0 = bf2f_lo(t0.w), l1 = bf2f_lo(t1.w), h0 = bf2f_hi(t0.w), h1 = bf2f_hi(t1.w);
        pk.w = pk2bf(lrelu(lo + l0 + w * (l1 - l0)), lrelu(hi + h0 + w * (h1 - h0)));
      }
      *(uint4*)(hA + le * 136 + sub * 32 + g * 8) = pk;
    }
  }
  __syncthreads();                       // #1: W1 staged + hA ready

  const uint16_t* aRow = hA + n15 * 136 + quad * 8;

  floatx4 acc[8];
#pragma unroll
  for (int nt = 0; nt < 8; ++nt) acc[nt] = (floatx4){0.f, 0.f, 0.f, 0.f};
  gemm_lds(wstage, aRow, lane, acc);     // L1, B from LDS

  __syncthreads();                       // #2: all waves done reading W1
  // stage W2 into same buffer -- drains at barrier 3, hidden under epilogue 1
#pragma unroll
  for (int j = 0; j < 8; ++j)
    gload_lds16(w2f + (wave * 8 + j) * 512 + lane * 8, wstage + (wave * 8 + j) * 512);

  // epilogue 1: +b1, LN, lrelu -> hA
  {
    float bv[8], wv[8], bb2[8];
#pragma unroll
    for (int nt = 0; nt < 8; ++nt) {
      int col = nt * 16 + n15;
      bv[nt] = b1[col]; wv[nt] = ln1w[col]; bb2[nt] = ln1b[col];
    }
    float s[4] = {0,0,0,0}, q[4] = {0,0,0,0};
#pragma unroll
    for (int nt = 0; nt < 8; ++nt)
#pragma unroll
      for (int r = 0; r < 4; ++r) { float v = acc[nt][r] + bv[nt]; s[r] += v; q[r] += v * v; }
#pragma unroll
    for (int m = 1; m <= 8; m <<= 1)
#pragma unroll
      for (int r = 0; r < 4; ++r) { s[r] += __shfl_xor(s[r], m); q[r] += __shfl_xor(q[r], m); }
    float mean[4], rstd[4];
#pragma unroll
    for (int r = 0; r < 4; ++r) {
      mean[r] = s[r] * (1.0f / 128.0f);
      float var = q[r] * (1.0f / 128.0f) - mean[r] * mean[r];
      rstd[r] = rsqrtf(var + 1e-5f);
    }
#pragma unroll
    for (int nt = 0; nt < 8; ++nt)
#pragma unroll
      for (int r = 0; r < 4; ++r) {
        float v = acc[nt][r] + bv[nt];
        float vn = (v - mean[r]) * rstd[r] * wv[nt] + bb2[nt];
        hA[(quad * 4 + r) * 136 + nt * 16 + n15] = bftrunc(lrelu(vn));
      }
  }
  __syncthreads();                       // #3: W2 staged (hA is wave-private)

#pragma unroll
  for (int nt = 0; nt < 8; ++nt) acc[nt] = (floatx4){0.f, 0.f, 0.f, 0.f};
  gemm_lds(wstage, aRow, lane, acc);     // L2, B from LDS

  // epilogue 2: +b2, LN, lrelu, force = h@Wo + bo, scatter atomics
  {
    float bv[8], wv[8], bb2[8], wo0[8], wo1[8];
#pragma unroll
    for (int nt = 0; nt < 8; ++nt) {
      int col = nt * 16 + n15;
      bv[nt] = b2[col]; wv[nt] = ln2w[col]; bb2[nt] = ln2b[col];
      wo0[nt] = Wo[2 * col]; wo1[nt] = Wo[2 * col + 1];
    }
    float s[4] = {0,0,0,0}, q[4] = {0,0,0,0};
#pragma unroll
    for (int nt = 0; nt < 8; ++nt)
#pragma unroll
      for (int r = 0; r < 4; ++r) { float v = acc[nt][r] + bv[nt]; s[r] += v; q[r] += v * v; }
#pragma unroll
    for (int m = 1; m <= 8; m <<= 1)
#pragma unroll
      for (int r = 0; r < 4; ++r) { s[r] += __shfl_xor(s[r], m); q[r] += __shfl_xor(q[r], m); }
    float mean[4], rstd[4];
#pragma unroll
    for (int r = 0; r < 4; ++r) {
      mean[r] = s[r] * (1.0f / 128.0f);
      float var = q[r] * (1.0f / 128.0f) - mean[r] * mean[r];
      rstd[r] = rsqrtf(var + 1e-5f);
    }
    float f0[4] = {0,0,0,0}, f1[4] = {0,0,0,0};
#pragma unroll
    for (int nt = 0; nt < 8; ++nt)
#pragma unroll
      for (int r = 0; r < 4; ++r) {
        float v = acc[nt][r] + bv[nt];
        float vn = lrelu((v - mean[r]) * rstd[r] * wv[nt] + bb2[nt]);
        f0[r] += vn * wo0[nt];
        f1[r] += vn * wo1[nt];
      }
#pragma unroll
    for (int m = 1; m <= 8; m <<= 1)
#pragma unroll
      for (int r = 0; r < 4; ++r) { f0[r] += __shfl_xor(f0[r], m); f1[r] += __shfl_xor(f1[r], m); }

    if (n15 < 4) {
      int gr = wave * 16 + quad * 4 + n15;
      int ge2 = blockIdx.x * 64 + gr;
      if (ge2 < N_EDGES) {
        float F0 = (n15 == 0) ? f0[0] : (n15 == 1) ? f0[1] : (n15 == 2) ? f0[2] : f0[3];
        float F1 = (n15 == 0) ? f1[0] : (n15 == 1) ? f1[1] : (n15 == 2) ? f1[2] : f1[3];
        F0 += bo[0]; F1 += bo[1];
        float ux = u_lds[gr][0], uy = u_lds[gr][1], uz = u_lds[gr][2];
        int ii = ij_lds[gr][0], jj = ij_lds[gr][1];
        float c0 = 0.5f * F0;          // STEP * force0, along +u
        float c1 = -0.5f * F1;         // STEP * force1, along -u
        atomicAdd(out + 3 * ii,     c0 * ux);
        atomicAdd(out + 3 * ii + 1, c0 * uy);
        atomicAdd(out + 3 * ii + 2, c0 * uz);
        atomicAdd(out + 3 * jj,     c1 * ux);
        atomicAdd(out + 3 * jj + 1, c1 * uy);
        atomicAdd(out + 3 * jj + 2, c1 * uz);
      }
    }
  }
}

extern "C" void kernel_launch(void* const* d_in, const int* in_sizes, int n_in,
                              void* d_out, int out_size, void* d_ws, size_t ws_size,
                              hipStream_t stream) {
  const float* x    = (const float*)d_in[0];
  const float* pos  = (const float*)d_in[1];
  const float* nemb = (const float*)d_in[2];
  const int*   bidx = (const int*)d_in[3];
  const int*   btyp = (const int*)d_in[4];
  const float* bemb = (const float*)d_in[5];
  const float* W0   = (const float*)d_in[6];
  const float* b0   = (const float*)d_in[7];
  const float* W1   = (const float*)d_in[8];
  const float* b1   = (const float*)d_in[9];
  const float* ln1w = (const float*)d_in[10];
  const float* ln1b = (const float*)d_in[11];
  const float* W2   = (const float*)d_in[12];
  const float* b2   = (const float*)d_in[13];
  const float* ln2w = (const float*)d_in[14];
  const float* ln2b = (const float*)d_in[15];
  const float* Wo   = (const float*)d_in[16];
  const float* bo   = (const float*)d_in[17];
  float* out = (float*)d_out;

  // ws: frag weights 128KB + be0 2KB + T 1.31MB + Pa/Pb 51.2MB
  uint16_t* w0ab = (uint16_t*)d_ws;                 // 32768 bf16
  uint16_t* w1f  = w0ab + 32768;                    // 16384
  uint16_t* w2f  = w1f + 16384;                     // 16384
  float*    be0f = (float*)(w2f + 16384);           // 512 f32
  uint16_t* Tt   = (uint16_t*)(be0f + 512);         // 4*TBINS*128 bf16
  uint16_t* Pa   = Tt + (size_t)4 * TBINS * 128;    // N_NODES*128 bf16
  uint16_t* Pb   = Pa + (size_t)N_NODES * 128;      // N_NODES*128 bf16

  prep0_kernel<<<(66048 + out_size + 255) / 256, 256, 0, stream>>>(
      W0, b0, W1, W2, bemb, w0ab, w1f, w2f, be0f, pos, out, out_size);
  prep_t_kernel<<<TBINS, 256, 0, stream>>>(W0, be0f, Tt);
  prep_p_kernel<<<(N_NODES + 64 * PREP_NG - 1) / (64 * PREP_NG), 256, 0, stream>>>(
      nemb, w0ab, Pa, Pb);
  bond_mlp_kernel<<<(N_EDGES + 63) / 64, 256, 0, stream>>>(
      x, bidx, btyp, Pa, Pb, Tt, w1f, w2f,
      b1, ln1w, ln1b, b2, ln2w, ln2b, Wo, bo, out);
}